// Round 2
// baseline (234.774 us; speedup 1.0000x reference)
//
#include <hip/hip_runtime.h>

// Problem constants (from reference setup_inputs)
#define BATCH 16
#define CIN   3
#define H     384
#define W     384
#define HO    382
#define WO    382
#define OFFC  18   // offset channels = 2*K
#define OOUT  3    // dcn output channels
#define KTAPS 9

__global__ __launch_bounds__(256)
void deform_fused_kernel(const float* __restrict__ x,
                         const float* __restrict__ conv_w,
                         const float* __restrict__ conv_b,
                         const float* __restrict__ dcn_w,
                         const float* __restrict__ dcn_b,
                         float* __restrict__ out)
{
    // Stage all weights in LDS (588 floats total).
    // NOTE: OFFC*27 = 486 > blockDim (256) -> must grid-stride the staging
    // loop (round-1 bug: single guarded store left elements 256..485 garbage).
    __shared__ float s_cw[OFFC * 27];  // conv_w  [18][3][3][3]
    __shared__ float s_cb[OFFC];       // conv_b  [18]
    __shared__ float s_dw[OOUT * 27];  // dcn_w   [3][3][9]
    __shared__ float s_db[OOUT];       // dcn_b   [3]

    const int t = threadIdx.x;
    for (int i = t; i < OFFC * 27; i += 256) s_cw[i] = conv_w[i];
    if (t < OFFC)      s_cb[t] = conv_b[t];
    if (t < OOUT * 27) s_dw[t] = dcn_w[t];
    if (t < OOUT)      s_db[t] = dcn_b[t];
    __syncthreads();

    const int total = BATCH * HO * WO;
    const int gid = blockIdx.x * 256 + t;
    if (gid >= total) return;

    const int wo  = gid % WO;
    const int tmp = gid / WO;
    const int ho  = tmp % HO;
    const int b   = tmp / HO;

    const float* xb = x + b * (CIN * H * W);

    // Load the 3x3x3 input patch (reused for the offset conv)
    float xp[CIN][3][3];
    #pragma unroll
    for (int c = 0; c < CIN; ++c) {
        const float* xc = xb + c * (H * W) + ho * W + wo;
        #pragma unroll
        for (int i = 0; i < 3; ++i)
            #pragma unroll
            for (int j = 0; j < 3; ++j)
                xp[c][i][j] = xc[i * W + j];
    }

    // Offset conv: 18 channels, 3x3 VALID at (ho, wo)
    float off[OFFC];
    #pragma unroll
    for (int o = 0; o < OFFC; ++o) {
        float a = s_cb[o];
        const float* wv = &s_cw[o * 27];
        #pragma unroll
        for (int c = 0; c < CIN; ++c)
            #pragma unroll
            for (int i = 0; i < 3; ++i)
                #pragma unroll
                for (int j = 0; j < 3; ++j)
                    a = fmaf(wv[c * 9 + i * 3 + j], xp[c][i][j], a);
        off[o] = a;
    }

    float acc0 = s_db[0];
    float acc1 = s_db[1];
    float acc2 = s_db[2];

    #pragma unroll
    for (int k = 0; k < KTAPS; ++k) {
        const int ky = k / 3;
        const int kx = k % 3;
        const float py = off[2 * k]     + (float)(ho + ky);
        const float px = off[2 * k + 1] + (float)(wo + kx);
        const float y0f = floorf(py);
        const float x0f = floorf(px);
        const float wy = py - y0f;
        const float wx = px - x0f;
        const int y0 = (int)y0f;
        const int x0 = (int)x0f;
        const int y1 = y0 + 1;
        const int x1 = x0 + 1;

        const bool vy0 = (y0 >= 0) && (y0 < H);
        const bool vy1 = (y1 >= 0) && (y1 < H);
        const bool vx0 = (x0 >= 0) && (x0 < W);
        const bool vx1 = (x1 >= 0) && (x1 < W);

        const int cy0 = min(max(y0, 0), H - 1);
        const int cy1 = min(max(y1, 0), H - 1);
        const int cx0 = min(max(x0, 0), W - 1);
        const int cx1 = min(max(x1, 0), W - 1);

        const float w00 = (vy0 && vx0) ? (1.f - wy) * (1.f - wx) : 0.f;
        const float w01 = (vy0 && vx1) ? (1.f - wy) * wx         : 0.f;
        const float w10 = (vy1 && vx0) ? wy * (1.f - wx)         : 0.f;
        const float w11 = (vy1 && vx1) ? wy * wx                 : 0.f;

        const int i00 = cy0 * W + cx0;
        const int i01 = cy0 * W + cx1;
        const int i10 = cy1 * W + cx0;
        const int i11 = cy1 * W + cx1;

        #pragma unroll
        for (int c = 0; c < CIN; ++c) {
            const float* xc = xb + c * (H * W);
            float s = xc[i00] * w00;
            s = fmaf(xc[i01], w01, s);
            s = fmaf(xc[i10], w10, s);
            s = fmaf(xc[i11], w11, s);
            acc0 = fmaf(s_dw[0 * 27 + c * 9 + k], s, acc0);
            acc1 = fmaf(s_dw[1 * 27 + c * 9 + k], s, acc1);
            acc2 = fmaf(s_dw[2 * 27 + c * 9 + k], s, acc2);
        }
    }

    const int obase = b * (OOUT * HO * WO) + ho * WO + wo;
    out[obase]                = acc0;
    out[obase + HO * WO]      = acc1;
    out[obase + 2 * HO * WO]  = acc2;
}

extern "C" void kernel_launch(void* const* d_in, const int* in_sizes, int n_in,
                              void* d_out, int out_size, void* d_ws, size_t ws_size,
                              hipStream_t stream) {
    const float* x      = (const float*)d_in[0];
    const float* conv_w = (const float*)d_in[1];
    const float* conv_b = (const float*)d_in[2];
    const float* dcn_w  = (const float*)d_in[3];
    const float* dcn_b  = (const float*)d_in[4];
    float* out = (float*)d_out;

    const int total = BATCH * HO * WO;
    const int blocks = (total + 255) / 256;
    deform_fused_kernel<<<blocks, 256, 0, stream>>>(x, conv_w, conv_b, dcn_w, dcn_b, out);
}